// Round 17
// baseline (95.491 us; speedup 1.0000x reference)
//
#include <hip/hip_runtime.h>
#include <math.h>

namespace {

constexpr int E_  = 768;
constexpr int H_  = 12;
constexpr int DH_ = 64;
constexpr int T_  = 2048;
constexpr int B_  = 2;
constexpr int M_  = B_ * T_;  // 4096
constexpr int BH_ = B_ * H_;  // 24
constexpr int NSPLIT = 2;     // attention k-range split factor

typedef __attribute__((ext_vector_type(8))) short bf16x8;
typedef __attribute__((ext_vector_type(4))) float f32x4;

__device__ inline ushort f2bf(float f) {
  union { float f; unsigned u; } v; v.f = f;
  unsigned u = v.u + 0x7FFFu + ((v.u >> 16) & 1u);  // RNE
  return (ushort)(u >> 16);
}
__device__ inline float bf2f(ushort u) {
  union { unsigned u; float f; } v; v.u = (unsigned)u << 16; return v.f;
}

// async global->LDS, 16B per lane (wave-uniform LDS base, per-lane global src)
__device__ __forceinline__ void gl16(const ushort* g, ushort* l) {
  __builtin_amdgcn_global_load_lds(
      (const __attribute__((address_space(1))) unsigned int*)(g),
      (__attribute__((address_space(3))) unsigned int*)(l), 16, 0, 0);
}

// ---------------------------------------------------------------------------
// prep: blocks [0,1536) convert x f32->bf16; blocks [1536,2112) transpose W.
// ---------------------------------------------------------------------------
constexpr int NCONV = 1536;

__global__ __launch_bounds__(256) void prep_k(
    const float* __restrict__ x,
    const float* __restrict__ Wq, const float* __restrict__ Wk,
    const float* __restrict__ Wv, const float* __restrict__ Wp,
    ushort* __restrict__ xb, ushort* __restrict__ Wt, ushort* __restrict__ Wpt)
{
  __shared__ float tile[64][65];
  const int bid = blockIdx.x;
  const int tid = threadIdx.x;

  if (bid < NCONV) {
    const size_t i = ((size_t)bid * 256 + tid) * 8;
    float4 a = *(const float4*)(x + i);
    float4 b = *(const float4*)(x + i + 4);
    ushort o[8] = {f2bf(a.x), f2bf(a.y), f2bf(a.z), f2bf(a.w),
                   f2bf(b.x), f2bf(b.y), f2bf(b.z), f2bf(b.w)};
    *(bf16x8*)(xb + i) = *(bf16x8*)o;
    return;
  }

  const int wb = bid - NCONV;  // 0..575
  const int tr = tid >> 4, tc = tid & 15;
  const float* src; ushort* dst;
  int k0, n0, sN, dK;
  if (wb < 432) {
    const int mat = wb / 144, rem = wb % 144;
    const int h = rem / 12, ktile = rem % 12;
    const float* W = (mat == 0) ? Wq : (mat == 1) ? Wk : Wv;
    src = W + (size_t)h * E_ * DH_;
    dst = Wt + (size_t)(mat * H_ + h) * DH_ * E_;
    k0 = ktile * 64; n0 = 0; sN = DH_; dK = E_;
  } else {
    const int rem = wb - 432;
    src = Wp;
    dst = Wpt;
    k0 = (rem / 12) * 64; n0 = (rem % 12) * 64; sN = E_; dK = E_;
  }

#pragma unroll
  for (int rr = 0; rr < 64; rr += 16) {
    float4 v = *(const float4*)(src + (size_t)(k0 + tr + rr) * sN + n0 + tc * 4);
    tile[tr + rr][tc * 4 + 0] = v.x;
    tile[tr + rr][tc * 4 + 1] = v.y;
    tile[tr + rr][tc * 4 + 2] = v.z;
    tile[tr + rr][tc * 4 + 3] = v.w;
  }
  __syncthreads();
#pragma unroll
  for (int rr = 0; rr < 64; rr += 16) {
    const int n = tr + rr;
    ushort4 o;
    o.x = f2bf(tile[tc * 4 + 0][n]);
    o.y = f2bf(tile[tc * 4 + 1][n]);
    o.z = f2bf(tile[tc * 4 + 2][n]);
    o.w = f2bf(tile[tc * 4 + 3][n]);
    *(ushort4*)(dst + (size_t)(n0 + n) * dK + k0 + tc * 4) = o;
  }
}

// ---------------------------------------------------------------------------
// QKV GEMM: 256x64 tiles, 512 threads (8 waves). Half the barrier events and
// half the B-staging per output vs 128x64. Same fragment math & epilogues.
// grid (36, 16). LDS 40 KB (As 32K | Bs 8K; V bounce reuses, stride 264).
// ---------------------------------------------------------------------------
constexpr float QSCALE = 0.18033688f;  // 1/8 * log2(e)

__global__ __launch_bounds__(512) void qkv_fused_k(
    const ushort* __restrict__ xb, const ushort* __restrict__ Wt,
    ushort* __restrict__ q_ws, ushort* __restrict__ k_ws, ushort* __restrict__ vt_ws)
{
  __shared__ __align__(16) ushort lds[(256 + 64) * 64];  // 40 KB
  ushort* As = lds;               // [256][64]
  ushort* Bs = lds + 256 * 64;    // [64][64]

  const int seg = blockIdx.x;     // 0..35: (mat, head)
  const int m0  = blockIdx.y * 256;
  const ushort* Wh = Wt + (size_t)seg * DH_ * E_;

  const int tid  = threadIdx.x;
  const int w    = tid >> 6, l = tid & 63;   // 8 waves
  const int lrow = l & 15, lk = l >> 4;
  const int r7   = lrow & 7;
  const int srow = l >> 3;
  const int sch  = (l & 7) ^ srow;

  f32x4 acc[2][4] = {};

  for (int k0 = 0; k0 < E_; k0 += 64) {
#pragma unroll
    for (int r = 0; r < 4; ++r) {
      const int base = r * 64 + w * 8;       // 8 waves x 8 rows x 4 iters = 256
      gl16(xb + (size_t)(m0 + base + srow) * E_ + k0 + sch * 8, &As[base * 64]);
    }
    {
      const int base = w * 8;                // 8 waves x 8 rows = 64
      gl16(Wh + (size_t)(base + srow) * E_ + k0 + sch * 8, &Bs[base * 64]);
    }
    __syncthreads();

#pragma unroll
    for (int kk = 0; kk < 2; ++kk) {
      const int cof = ((kk * 4 + lk) ^ r7) * 8;
      const bf16x8 a0 = *(const bf16x8*)&As[(w * 32 + lrow) * 64 + cof];
      const bf16x8 a1 = *(const bf16x8*)&As[(w * 32 + 16 + lrow) * 64 + cof];
#pragma unroll
      for (int nf = 0; nf < 4; ++nf) {
        const bf16x8 b = *(const bf16x8*)&Bs[(nf * 16 + lrow) * 64 + cof];
        acc[0][nf] = __builtin_amdgcn_mfma_f32_16x16x32_bf16(a0, b, acc[0][nf], 0, 0, 0);
        acc[1][nf] = __builtin_amdgcn_mfma_f32_16x16x32_bf16(a1, b, acc[1][nf], 0, 0, 0);
      }
    }
    __syncthreads();
  }

  const int b   = m0 >> 11;       // 256-row tiles never straddle batch (2048%256==0)
  const int t0  = m0 & 2047;
  const int mat = seg / H_;
  const int h   = seg - mat * H_;
  const int bh  = b * H_ + h;

  if (mat != 2) {
    const float qs = (mat == 0) ? QSCALE : 1.0f;
    ushort* outw = (mat == 0) ? q_ws : k_ws;
#pragma unroll
    for (int mi = 0; mi < 2; ++mi)
#pragma unroll
      for (int i = 0; i < 4; ++i) {
        const int t = t0 + w * 32 + mi * 16 + lk * 4 + i;
        ushort* orow = outw + ((size_t)bh * T_ + t) * DH_;
#pragma unroll
        for (int nf = 0; nf < 4; ++nf)
          orow[nf * 16 + lrow] = f2bf(acc[mi][nf][i] * qs);
      }
  } else {
    // V: transpose 256x64 tile via LDS bounce -> vt_ws[bh][d][t]
    ushort* Td = lds;  // [64][264] = 33.8 KB (fits in the 40 KB array)
    __syncthreads();
#pragma unroll
    for (int mi = 0; mi < 2; ++mi)
#pragma unroll
      for (int i = 0; i < 4; ++i) {
        const int tl = w * 32 + mi * 16 + lk * 4 + i;
#pragma unroll
        for (int nf = 0; nf < 4; ++nf)
          Td[(nf * 16 + lrow) * 264 + tl] = f2bf(acc[mi][nf][i]);
      }
    __syncthreads();
#pragma unroll
    for (int it = 0; it < 4; ++it) {
      const int c = tid + it * 512;          // 2048 chunks of 8 bf16
      const int d = c >> 5, sub = c & 31;
      *(bf16x8*)(vt_ws + ((size_t)bh * DH_ + d) * T_ + t0 + sub * 8) =
          *(const bf16x8*)&Td[d * 264 + sub * 8];
    }
  }
}

// ---------------------------------------------------------------------------
// Causal flash attention, split x2, QBLK=128, DOUBLE-BUFFERED K/V with ONE
// barrier per tile (48 KB LDS -> 3 blocks/CU; grid provides exactly 3/CU, so
// the double-buffer is occupancy-free here). Skip-guard for fully-masked
// waves (R16 NaN fix). Per-wave swizzled P bounce, defer-max, exp2 domain.
// ---------------------------------------------------------------------------
__global__ __launch_bounds__(512) void attn_split_k(
    const ushort* __restrict__ q_ws, const ushort* __restrict__ k_ws,
    const ushort* __restrict__ vt_ws, ushort* __restrict__ op_ws,
    float2* __restrict__ ml_ws)
{
  __shared__ __align__(16) ushort Ks[2][64 * 64];  // 16 KB
  __shared__ __align__(16) ushort Vt[2][64 * 64];  // 16 KB
  __shared__ __align__(16) ushort Pl[8][16 * 64];  // 16 KB

  const int qt = 15 - (int)blockIdx.y;     // 128-row q-tile, long first
  const int bh = blockIdx.x;
  const int hz = blockIdx.z;               // 0..NSPLIT-1
  const int nt = 2 * qt + 2;               // 64-wide k-tiles in causal range
  const int klo = (hz * nt) / NSPLIT;
  const int khi = ((hz + 1) * nt) / NSPLIT;
  const int q0 = qt * 128;

  const ushort* Qb  = q_ws + (size_t)bh * T_ * DH_;
  const ushort* Kb  = k_ws + (size_t)bh * T_ * DH_;
  const ushort* VTb = vt_ws + (size_t)bh * DH_ * T_;

  const int tid  = threadIdx.x;
  const int w    = tid >> 6;        // 0..7
  const int l    = tid & 63;
  const int lrow = l & 15;
  const int lk   = l >> 4;
  const int r7   = lrow & 7;
  const int rr   = tid >> 3;        // staging row 0..63
  const int sub  = tid & 7;
  const int swc  = sub ^ (rr & 7);

  const int st0 = rr * 64 + swc * 8;

  int kof0[4], kof1[4];
#pragma unroll
  for (int ct = 0; ct < 4; ++ct) {
    kof0[ct] = (ct * 16 + lrow) * 64 + ((lk ^ r7) * 8);
    kof1[ct] = (ct * 16 + lrow) * 64 + (((lk + 4) ^ r7) * 8);
  }

  const ushort* Qrow = Qb + (size_t)(q0 + w * 16 + lrow) * DH_;
  const bf16x8 qa0 = *(const bf16x8*)(Qrow + lk * 8);
  const bf16x8 qa1 = *(const bf16x8*)(Qrow + lk * 8 + 32);
  const int qglob = q0 + w * 16 + lrow;
  const int qwmin = q0 + w * 16;

  float m_r = -INFINITY, l_r = 0.f;
  f32x4 oc[4] = {};

  ushort* Pw = &Pl[w][0];
  const int rd0 = lrow * 64 + ((lk ^ r7) * 8);
  const int rd1 = lrow * 64 + (((lk + 4) ^ r7) * 8);
  const int wrbase  = lrow * 128 + (lk & 1) * 8;
  const int wrchunk = (lk >> 1);

  {
    // prologue: tile klo -> regs -> buf 0
    bf16x8 kp = *(const bf16x8*)(Kb + (size_t)(klo * 64 + rr) * DH_ + sub * 8);
    bf16x8 vp = *(const bf16x8*)(VTb + (size_t)rr * T_ + klo * 64 + sub * 8);
    *(bf16x8*)&Ks[0][st0] = kp;
    *(bf16x8*)&Vt[0][st0] = vp;
    __syncthreads();

    for (int kt = klo; kt < khi; ++kt) {
      const int s0  = kt * 64;
      const int cur = (kt - klo) & 1;

      // issue next tile's global loads early (hide under compute)
      if (kt + 1 < khi) {
        const int sn = s0 + 64;
        kp = *(const bf16x8*)(Kb + (size_t)(sn + rr) * DH_ + sub * 8);
        vp = *(const bf16x8*)(VTb + (size_t)rr * T_ + sn + sub * 8);
      }

      // wave-uniform: s0 > qwmin => tile fully masked for this wave -> skip
      if (s0 <= qwmin) {
        // S^T = K Q^T
        f32x4 st[4];
#pragma unroll
        for (int ct = 0; ct < 4; ++ct) {
          const bf16x8 kb0 = *(const bf16x8*)&Ks[cur][kof0[ct]];
          const bf16x8 kb1 = *(const bf16x8*)&Ks[cur][kof1[ct]];
          f32x4 z = {0.f, 0.f, 0.f, 0.f};
          z = __builtin_amdgcn_mfma_f32_16x16x32_bf16(kb0, qa0, z, 0, 0, 0);
          st[ct] = __builtin_amdgcn_mfma_f32_16x16x32_bf16(kb1, qa1, z, 0, 0, 0);
        }

        if (s0 + 63 > qwmin) {  // partial (diagonal) tile for this wave
#pragma unroll
          for (int ct = 0; ct < 4; ++ct)
#pragma unroll
            for (int i = 0; i < 4; ++i)
              if (s0 + ct * 16 + lk * 4 + i > qglob) st[ct][i] = -INFINITY;
        }

        float mc[4];
#pragma unroll
        for (int ct = 0; ct < 4; ++ct)
          mc[ct] = fmaxf(fmaxf(st[ct][0], st[ct][1]), fmaxf(st[ct][2], st[ct][3]));
        float mx = fmaxf(fmaxf(mc[0], mc[1]), fmaxf(mc[2], mc[3]));
        mx = fmaxf(mx, __shfl_xor(mx, 16));
        mx = fmaxf(mx, __shfl_xor(mx, 32));

        if (__any(mx > m_r + 8.f)) {
          const float mn   = fmaxf(m_r, mx);
          const float corr = exp2f(m_r - mn);
          m_r = mn;
          l_r *= corr;
#pragma unroll
          for (int i = 0; i < 4; ++i) {
            const float cr = __shfl(corr, lk * 4 + i);
#pragma unroll
            for (int ct = 0; ct < 4; ++ct) oc[ct][i] *= cr;
          }
        }

        float sc[4];
#pragma unroll
        for (int ct = 0; ct < 4; ++ct) {
#pragma unroll
          for (int i = 0; i < 4; ++i) st[ct][i] = exp2f(st[ct][i] - m_r);
          sc[ct] = (st[ct][0] + st[ct][1]) + (st[ct][2] + st[ct][3]);
        }
        float rs = (sc[0] + sc[1]) + (sc[2] + sc[3]);
        rs += __shfl_xor(rs, 16);
        rs += __shfl_xor(rs, 32);
        l_r += rs;

        // P^T -> per-wave LDS (packed bf16, swizzled 8B stores; no barrier)
#pragma unroll
        for (int ct = 0; ct < 4; ++ct) {
          unsigned lo, hi;
          asm("v_cvt_pk_bf16_f32 %0, %1, %2" : "=v"(lo) : "v"(st[ct][0]), "v"(st[ct][1]));
          asm("v_cvt_pk_bf16_f32 %0, %1, %2" : "=v"(hi) : "v"(st[ct][2]), "v"(st[ct][3]));
          uint2 pk; pk.x = lo; pk.y = hi;
          const int ch = ((ct * 2 + wrchunk) ^ r7);
          *(uint2*)((char*)Pw + wrbase + ch * 16) = pk;
        }

        const bf16x8 pa0 = *(const bf16x8*)(Pw + rd0);
        const bf16x8 pa1 = *(const bf16x8*)(Pw + rd1);

        // O += P V
#pragma unroll
        for (int ct = 0; ct < 4; ++ct) {
          const bf16x8 vb0 = *(const bf16x8*)&Vt[cur][kof0[ct]];
          const bf16x8 vb1 = *(const bf16x8*)&Vt[cur][kof1[ct]];
          oc[ct] = __builtin_amdgcn_mfma_f32_16x16x32_bf16(pa0, vb0, oc[ct], 0, 0, 0);
          oc[ct] = __builtin_amdgcn_mfma_f32_16x16x32_bf16(pa1, vb1, oc[ct], 0, 0, 0);
        }
      }

      // commit next tile into the other buffer; ONE barrier per tile
      if (kt + 1 < khi) {
        const int nxt = cur ^ 1;
        *(bf16x8*)&Ks[nxt][st0] = kp;
        *(bf16x8*)&Vt[nxt][st0] = vp;
      }
      __syncthreads();
    }
  }

  // epilogue (R8-proven): unnormalized partial O + per-row (m,l)
  const size_t pb = (size_t)(hz * BH_ + bh) * T_;
  if (lk == 0)
    ml_ws[pb + q0 + w * 16 + lrow] = make_float2(m_r, l_r);
#pragma unroll
  for (int i = 0; i < 4; ++i) {
    const int t = q0 + w * 16 + lk * 4 + i;
    ushort* orow = op_ws + (pb + t) * DH_;
#pragma unroll
    for (int ct = 0; ct < 4; ++ct)
      orow[ct * 16 + lrow] = f2bf(oc[ct][i]);
  }
}

// ---------------------------------------------------------------------------
// Out-proj GEMM with fused split-k combine (64x64 tiles, R9-proven).
// Handles (m=-inf, l=0) padding splits exactly: exp2(-inf - m) = 0.
// ---------------------------------------------------------------------------
__global__ __launch_bounds__(256) void proj_fused_k(
    const ushort* __restrict__ op_ws, const float2* __restrict__ ml_ws,
    const ushort* __restrict__ Wpt, const float* __restrict__ bp,
    float* __restrict__ out)
{
  __shared__ __align__(16) ushort lds[(64 + 64) * 64];  // As | Bs (16 KB)
  ushort* As = lds;
  ushort* Bs = lds + 64 * 64;

  const int n0 = blockIdx.x * 64;
  const int m0 = blockIdx.y * 64;
  const int b  = m0 >> 11;
  const int t0 = m0 & 2047;

  const int tid  = threadIdx.x;
  const int w    = tid >> 6, l = tid & 63;
  const int lrow = l & 15, lk = l >> 4;
  const int r7   = lrow & 7;
  const int srow = l >> 3;
  const int sch  = (l & 7) ^ srow;
  const int ar = tid >> 2;          // A-staging row 0..63
  const int cc = tid & 3;           // 16-elem chunk
  const int a7 = ar & 7;

  f32x4 acc[4] = {};

  for (int k0 = 0; k0 < E_; k0 += 64) {
    const int h  = k0 >> 6;
    const int bh = b * H_ + h;

#pragma unroll
    for (int r = 0; r < 2; ++r) {
      const int base = r * 32 + w * 8;
      gl16(Wpt + (size_t)(n0 + base + srow) * E_ + k0 + sch * 8, &Bs[base * 64]);
    }

    // A staging: combine NSPLIT partials in regs, swizzled ds_write
    {
      const int t = t0 + ar;
      size_t ix[NSPLIT];
      float2 ml[NSPLIT];
#pragma unroll
      for (int z = 0; z < NSPLIT; ++z) {
        ix[z] = ((size_t)(z * BH_ + bh) * T_ + t);
        ml[z] = ml_ws[ix[z]];
      }
      float m = ml[0].x;
#pragma unroll
      for (int z = 1; z < NSPLIT; ++z) m = fmaxf(m, ml[z].x);
      float f[NSPLIT];
      float den = 0.f;
#pragma unroll
      for (int z = 0; z < NSPLIT; ++z) {
        f[z] = exp2f(ml[z].x - m);
        den += f[z] * ml[z].y;
      }
      const float inv = 1.0f / den;
#pragma unroll
      for (int z = 0; z < NSPLIT; ++z) f[z] *= inv;

      float o[16] = {};
#pragma unroll
      for (int z = 0; z < NSPLIT; ++z) {
        const ushort* p = op_ws + ix[z] * DH_ + cc * 16;
        bf16x8 x0 = *(const bf16x8*)p;
        bf16x8 x1 = *(const bf16x8*)(p + 8);
#pragma unroll
        for (int j = 0; j < 8; ++j) {
          o[j]     += f[z] * bf2f((ushort)x0[j]);
          o[8 + j] += f[z] * bf2f((ushort)x1[j]);
        }
      }
      ushort ob[16];
#pragma unroll
      for (int j = 0; j < 16; ++j) ob[j] = f2bf(o[j]);
      *(bf16x8*)&As[ar * 64 + ((2 * cc) ^ a7) * 8]     = *(const bf16x8*)&ob[0];
      *(bf16x8*)&As[ar * 64 + ((2 * cc + 1) ^ a7) * 8] = *(const bf16x8*)&ob[8];
    }
    __syncthreads();

#pragma unroll
    for (int kk = 0; kk < 2; ++kk) {
      const int cof = ((kk * 4 + lk) ^ r7) * 8;
      const bf16x8 a = *(const bf16x8*)&As[(w * 16 + lrow) * 64 + cof];
#pragma unroll
      for (int nf = 0; nf < 4; ++nf) {
        const bf16x8 bb = *(const bf16x8*)&Bs[(nf * 16 + lrow) * 64 + cof];
        acc[nf] = __builtin_amdgcn_mfma_f32_16x16x32_bf16(a, bb, acc[nf], 0, 0, 0);
      }
    }
    __syncthreads();
  }

  float bias[4];
#pragma unroll
  for (int nf = 0; nf < 4; ++nf) bias[nf] = bp[n0 + nf * 16 + lrow];

#pragma unroll
  for (int i = 0; i < 4; ++i) {
    const int m = m0 + w * 16 + lk * 4 + i;
    float* orow = out + (size_t)m * E_ + n0;
#pragma unroll
    for (int nf = 0; nf < 4; ++nf)
      orow[nf * 16 + lrow] = acc[nf][i] + bias[nf];
  }
}

}  // namespace

extern "C" void kernel_launch(void* const* d_in, const int* in_sizes, int n_in,
                              void* d_out, int out_size, void* d_ws, size_t ws_size,
                              hipStream_t stream) {
  const float* x  = (const float*)d_in[0];
  const float* Wq = (const float*)d_in[1];
  const float* Wk = (const float*)d_in[2];
  const float* Wv = (const float*)d_in[3];
  const float* Wp = (const float*)d_in[4];
  const float* bp = (const float*)d_in[5];
  float* out = (float*)d_out;

  const size_t nx  = (size_t)M_ * E_;            // 3,145,728
  const size_t nwt = (size_t)3 * H_ * DH_ * E_;  // 1,769,472
  const size_t nwp = (size_t)E_ * E_;            // 589,824
  const size_t per = (size_t)BH_ * T_ * DH_;     // 3,145,728

  ushort* xb    = (ushort*)d_ws;
  ushort* Wt    = xb + nx;
  ushort* Wpt   = Wt + nwt;
  ushort* q_ws  = Wpt + nwp;
  ushort* k_ws  = q_ws + per;
  ushort* vt_ws = k_ws + per;     // [bh][d][t]
  ushort* op_ws = vt_ws + per;    // [NSPLIT][bh][t][64] partials
  float2* ml_ws = (float2*)(op_ws + NSPLIT * per);  // [NSPLIT][bh][t]

  prep_k<<<dim3(NCONV + 576), 256, 0, stream>>>(x, Wq, Wk, Wv, Wp, xb, Wt, Wpt);
  qkv_fused_k<<<dim3(36, 16), 512, 0, stream>>>(xb, Wt, q_ws, k_ws, vt_ws);
  attn_split_k<<<dim3(24, 16, NSPLIT), 512, 0, stream>>>(q_ws, k_ws, vt_ws, op_ws, ml_ws);
  proj_fused_k<<<dim3(12, 64), 256, 0, stream>>>(op_ws, ml_ws, Wpt, bp, out);
}

// Round 18
// 93.014 us; speedup vs baseline: 1.0266x; 1.0266x over previous
//
#include <hip/hip_runtime.h>
#include <math.h>

namespace {

constexpr int E_  = 768;
constexpr int H_  = 12;
constexpr int DH_ = 64;
constexpr int T_  = 2048;
constexpr int B_  = 2;
constexpr int M_  = B_ * T_;  // 4096
constexpr int BH_ = B_ * H_;  // 24
constexpr int NSPLIT = 2;     // attention k-range split factor

typedef __attribute__((ext_vector_type(8))) short bf16x8;
typedef __attribute__((ext_vector_type(4))) float f32x4;

__device__ inline ushort f2bf(float f) {
  union { float f; unsigned u; } v; v.f = f;
  unsigned u = v.u + 0x7FFFu + ((v.u >> 16) & 1u);  // RNE
  return (ushort)(u >> 16);
}
__device__ inline float bf2f(ushort u) {
  union { unsigned u; float f; } v; v.u = (unsigned)u << 16; return v.f;
}

// async global->LDS, 16B per lane (wave-uniform LDS base, per-lane global src)
__device__ __forceinline__ void gl16(const ushort* g, ushort* l) {
  __builtin_amdgcn_global_load_lds(
      (const __attribute__((address_space(1))) unsigned int*)(g),
      (__attribute__((address_space(3))) unsigned int*)(l), 16, 0, 0);
}

// ---------------------------------------------------------------------------
// prep: blocks [0,1536) convert x f32->bf16; blocks [1536,2112) transpose W.
// ---------------------------------------------------------------------------
constexpr int NCONV = 1536;

__global__ __launch_bounds__(256) void prep_k(
    const float* __restrict__ x,
    const float* __restrict__ Wq, const float* __restrict__ Wk,
    const float* __restrict__ Wv, const float* __restrict__ Wp,
    ushort* __restrict__ xb, ushort* __restrict__ Wt, ushort* __restrict__ Wpt)
{
  __shared__ float tile[64][65];
  const int bid = blockIdx.x;
  const int tid = threadIdx.x;

  if (bid < NCONV) {
    const size_t i = ((size_t)bid * 256 + tid) * 8;
    float4 a = *(const float4*)(x + i);
    float4 b = *(const float4*)(x + i + 4);
    ushort o[8] = {f2bf(a.x), f2bf(a.y), f2bf(a.z), f2bf(a.w),
                   f2bf(b.x), f2bf(b.y), f2bf(b.z), f2bf(b.w)};
    *(bf16x8*)(xb + i) = *(bf16x8*)o;
    return;
  }

  const int wb = bid - NCONV;  // 0..575
  const int tr = tid >> 4, tc = tid & 15;
  const float* src; ushort* dst;
  int k0, n0, sN, dK;
  if (wb < 432) {
    const int mat = wb / 144, rem = wb % 144;
    const int h = rem / 12, ktile = rem % 12;
    const float* W = (mat == 0) ? Wq : (mat == 1) ? Wk : Wv;
    src = W + (size_t)h * E_ * DH_;
    dst = Wt + (size_t)(mat * H_ + h) * DH_ * E_;
    k0 = ktile * 64; n0 = 0; sN = DH_; dK = E_;
  } else {
    const int rem = wb - 432;
    src = Wp;
    dst = Wpt;
    k0 = (rem / 12) * 64; n0 = (rem % 12) * 64; sN = E_; dK = E_;
  }

#pragma unroll
  for (int rr = 0; rr < 64; rr += 16) {
    float4 v = *(const float4*)(src + (size_t)(k0 + tr + rr) * sN + n0 + tc * 4);
    tile[tr + rr][tc * 4 + 0] = v.x;
    tile[tr + rr][tc * 4 + 1] = v.y;
    tile[tr + rr][tc * 4 + 2] = v.z;
    tile[tr + rr][tc * 4 + 3] = v.w;
  }
  __syncthreads();
#pragma unroll
  for (int rr = 0; rr < 64; rr += 16) {
    const int n = tr + rr;
    ushort4 o;
    o.x = f2bf(tile[tc * 4 + 0][n]);
    o.y = f2bf(tile[tc * 4 + 1][n]);
    o.z = f2bf(tile[tc * 4 + 2][n]);
    o.w = f2bf(tile[tc * 4 + 3][n]);
    *(ushort4*)(dst + (size_t)(n0 + n) * dK + k0 + tc * 4) = o;
  }
}

// ---------------------------------------------------------------------------
// QKV GEMM: 256x64 tiles, 512 threads (8 waves) — R17's version, kept for
// clean A/B vs R16's 128x64 (attn reverted below). grid (36, 16).
// ---------------------------------------------------------------------------
constexpr float QSCALE = 0.18033688f;  // 1/8 * log2(e)

__global__ __launch_bounds__(512) void qkv_fused_k(
    const ushort* __restrict__ xb, const ushort* __restrict__ Wt,
    ushort* __restrict__ q_ws, ushort* __restrict__ k_ws, ushort* __restrict__ vt_ws)
{
  __shared__ __align__(16) ushort lds[(256 + 64) * 64];  // 40 KB
  ushort* As = lds;               // [256][64]
  ushort* Bs = lds + 256 * 64;    // [64][64]

  const int seg = blockIdx.x;     // 0..35: (mat, head)
  const int m0  = blockIdx.y * 256;
  const ushort* Wh = Wt + (size_t)seg * DH_ * E_;

  const int tid  = threadIdx.x;
  const int w    = tid >> 6, l = tid & 63;   // 8 waves
  const int lrow = l & 15, lk = l >> 4;
  const int r7   = lrow & 7;
  const int srow = l >> 3;
  const int sch  = (l & 7) ^ srow;

  f32x4 acc[2][4] = {};

  for (int k0 = 0; k0 < E_; k0 += 64) {
#pragma unroll
    for (int r = 0; r < 4; ++r) {
      const int base = r * 64 + w * 8;
      gl16(xb + (size_t)(m0 + base + srow) * E_ + k0 + sch * 8, &As[base * 64]);
    }
    {
      const int base = w * 8;
      gl16(Wh + (size_t)(base + srow) * E_ + k0 + sch * 8, &Bs[base * 64]);
    }
    __syncthreads();

#pragma unroll
    for (int kk = 0; kk < 2; ++kk) {
      const int cof = ((kk * 4 + lk) ^ r7) * 8;
      const bf16x8 a0 = *(const bf16x8*)&As[(w * 32 + lrow) * 64 + cof];
      const bf16x8 a1 = *(const bf16x8*)&As[(w * 32 + 16 + lrow) * 64 + cof];
#pragma unroll
      for (int nf = 0; nf < 4; ++nf) {
        const bf16x8 b = *(const bf16x8*)&Bs[(nf * 16 + lrow) * 64 + cof];
        acc[0][nf] = __builtin_amdgcn_mfma_f32_16x16x32_bf16(a0, b, acc[0][nf], 0, 0, 0);
        acc[1][nf] = __builtin_amdgcn_mfma_f32_16x16x32_bf16(a1, b, acc[1][nf], 0, 0, 0);
      }
    }
    __syncthreads();
  }

  const int b   = m0 >> 11;
  const int t0  = m0 & 2047;
  const int mat = seg / H_;
  const int h   = seg - mat * H_;
  const int bh  = b * H_ + h;

  if (mat != 2) {
    const float qs = (mat == 0) ? QSCALE : 1.0f;
    ushort* outw = (mat == 0) ? q_ws : k_ws;
#pragma unroll
    for (int mi = 0; mi < 2; ++mi)
#pragma unroll
      for (int i = 0; i < 4; ++i) {
        const int t = t0 + w * 32 + mi * 16 + lk * 4 + i;
        ushort* orow = outw + ((size_t)bh * T_ + t) * DH_;
#pragma unroll
        for (int nf = 0; nf < 4; ++nf)
          orow[nf * 16 + lrow] = f2bf(acc[mi][nf][i] * qs);
      }
  } else {
    // V: transpose 256x64 tile via LDS bounce -> vt_ws[bh][d][t]
    ushort* Td = lds;  // [64][264]
    __syncthreads();
#pragma unroll
    for (int mi = 0; mi < 2; ++mi)
#pragma unroll
      for (int i = 0; i < 4; ++i) {
        const int tl = w * 32 + mi * 16 + lk * 4 + i;
#pragma unroll
        for (int nf = 0; nf < 4; ++nf)
          Td[(nf * 16 + lrow) * 264 + tl] = f2bf(acc[mi][nf][i]);
      }
    __syncthreads();
#pragma unroll
    for (int it = 0; it < 4; ++it) {
      const int c = tid + it * 512;
      const int d = c >> 5, sub = c & 31;
      *(bf16x8*)(vt_ws + ((size_t)bh * DH_ + d) * T_ + t0 + sub * 8) =
          *(const bf16x8*)&Td[d * 264 + sub * 8];
    }
  }
}

// ---------------------------------------------------------------------------
// Causal flash attention — R16-EXACT (proven 90.27 µs config): split x2,
// QBLK=128 (512 threads), single-buffered K/V with 2 barriers/tile, 32 KB
// LDS, skip-guard for fully-masked waves, per-wave swizzled P bounce,
// defer-max, exp2 domain. grid (24, 16, 2), long q-tiles first.
// ---------------------------------------------------------------------------
__global__ __launch_bounds__(512) void attn_split_k(
    const ushort* __restrict__ q_ws, const ushort* __restrict__ k_ws,
    const ushort* __restrict__ vt_ws, ushort* __restrict__ op_ws,
    float2* __restrict__ ml_ws)
{
  __shared__ __align__(16) ushort Ks[64 * 64];     // K tile [s][e], swizzled
  __shared__ __align__(16) ushort Vt[64 * 64];     // V^T tile [d][s], swizzled
  __shared__ __align__(16) ushort Pl[8][16 * 64];  // per-wave P [q][s], swizzled

  const int qt = 15 - (int)blockIdx.y;     // 128-row q-tile, long first
  const int bh = blockIdx.x;
  const int hz = blockIdx.z;               // 0..NSPLIT-1
  const int nt = 2 * qt + 2;               // 64-wide k-tiles in causal range
  const int klo = (hz * nt) / NSPLIT;
  const int khi = ((hz + 1) * nt) / NSPLIT;
  const int q0 = qt * 128;

  const ushort* Qb  = q_ws + (size_t)bh * T_ * DH_;
  const ushort* Kb  = k_ws + (size_t)bh * T_ * DH_;
  const ushort* VTb = vt_ws + (size_t)bh * DH_ * T_;

  const int tid  = threadIdx.x;
  const int w    = tid >> 6;        // 0..7
  const int l    = tid & 63;
  const int lrow = l & 15;
  const int lk   = l >> 4;
  const int r7   = lrow & 7;
  const int rr   = tid >> 3;        // staging row 0..63
  const int sub  = tid & 7;
  const int swc  = sub ^ (rr & 7);

  const int st0 = rr * 64 + swc * 8;

  int kof0[4], kof1[4];
#pragma unroll
  for (int ct = 0; ct < 4; ++ct) {
    kof0[ct] = (ct * 16 + lrow) * 64 + ((lk ^ r7) * 8);
    kof1[ct] = (ct * 16 + lrow) * 64 + (((lk + 4) ^ r7) * 8);
  }

  const ushort* Qrow = Qb + (size_t)(q0 + w * 16 + lrow) * DH_;
  const bf16x8 qa0 = *(const bf16x8*)(Qrow + lk * 8);
  const bf16x8 qa1 = *(const bf16x8*)(Qrow + lk * 8 + 32);
  const int qglob = q0 + w * 16 + lrow;
  const int qwmin = q0 + w * 16;

  float m_r = -INFINITY, l_r = 0.f;
  f32x4 oc[4] = {};

  ushort* Pw = &Pl[w][0];
  const int rd0 = lrow * 64 + ((lk ^ r7) * 8);
  const int rd1 = lrow * 64 + (((lk + 4) ^ r7) * 8);
  const int wrbase  = lrow * 128 + (lk & 1) * 8;
  const int wrchunk = (lk >> 1);

  {
    // prologue: tile klo -> regs
    bf16x8 kp = *(const bf16x8*)(Kb + (size_t)(klo * 64 + rr) * DH_ + sub * 8);
    bf16x8 vp = *(const bf16x8*)(VTb + (size_t)rr * T_ + klo * 64 + sub * 8);

    for (int kt = klo; kt < khi; ++kt) {
      const int s0 = kt * 64;

      // commit staged regs -> LDS; barrier opens compute phase
      *(bf16x8*)&Ks[st0] = kp;
      *(bf16x8*)&Vt[st0] = vp;
      __syncthreads();

      // issue next tile's global loads; latency hides under compute
      if (kt + 1 < khi) {
        const int sn = s0 + 64;
        kp = *(const bf16x8*)(Kb + (size_t)(sn + rr) * DH_ + sub * 8);
        vp = *(const bf16x8*)(VTb + (size_t)rr * T_ + sn + sub * 8);
      }

      // wave-uniform: s0 > qwmin => tile fully masked for this wave -> skip
      if (s0 <= qwmin) {
        // S^T = K Q^T
        f32x4 st[4];
#pragma unroll
        for (int ct = 0; ct < 4; ++ct) {
          const bf16x8 kb0 = *(const bf16x8*)&Ks[kof0[ct]];
          const bf16x8 kb1 = *(const bf16x8*)&Ks[kof1[ct]];
          f32x4 z = {0.f, 0.f, 0.f, 0.f};
          z = __builtin_amdgcn_mfma_f32_16x16x32_bf16(kb0, qa0, z, 0, 0, 0);
          st[ct] = __builtin_amdgcn_mfma_f32_16x16x32_bf16(kb1, qa1, z, 0, 0, 0);
        }

        if (s0 + 63 > qwmin) {  // partial (diagonal) tile for this wave
#pragma unroll
          for (int ct = 0; ct < 4; ++ct)
#pragma unroll
            for (int i = 0; i < 4; ++i)
              if (s0 + ct * 16 + lk * 4 + i > qglob) st[ct][i] = -INFINITY;
        }

        float mc[4];
#pragma unroll
        for (int ct = 0; ct < 4; ++ct)
          mc[ct] = fmaxf(fmaxf(st[ct][0], st[ct][1]), fmaxf(st[ct][2], st[ct][3]));
        float mx = fmaxf(fmaxf(mc[0], mc[1]), fmaxf(mc[2], mc[3]));
        mx = fmaxf(mx, __shfl_xor(mx, 16));
        mx = fmaxf(mx, __shfl_xor(mx, 32));

        if (__any(mx > m_r + 8.f)) {
          const float mn   = fmaxf(m_r, mx);
          const float corr = exp2f(m_r - mn);
          m_r = mn;
          l_r *= corr;
#pragma unroll
          for (int i = 0; i < 4; ++i) {
            const float cr = __shfl(corr, lk * 4 + i);
#pragma unroll
            for (int ct = 0; ct < 4; ++ct) oc[ct][i] *= cr;
          }
        }

        float sc[4];
#pragma unroll
        for (int ct = 0; ct < 4; ++ct) {
#pragma unroll
          for (int i = 0; i < 4; ++i) st[ct][i] = exp2f(st[ct][i] - m_r);
          sc[ct] = (st[ct][0] + st[ct][1]) + (st[ct][2] + st[ct][3]);
        }
        float rs = (sc[0] + sc[1]) + (sc[2] + sc[3]);
        rs += __shfl_xor(rs, 16);
        rs += __shfl_xor(rs, 32);
        l_r += rs;

        // P^T -> per-wave LDS (packed bf16, swizzled 8B stores; no barrier)
#pragma unroll
        for (int ct = 0; ct < 4; ++ct) {
          unsigned lo, hi;
          asm("v_cvt_pk_bf16_f32 %0, %1, %2" : "=v"(lo) : "v"(st[ct][0]), "v"(st[ct][1]));
          asm("v_cvt_pk_bf16_f32 %0, %1, %2" : "=v"(hi) : "v"(st[ct][2]), "v"(st[ct][3]));
          uint2 pk; pk.x = lo; pk.y = hi;
          const int ch = ((ct * 2 + wrchunk) ^ r7);
          *(uint2*)((char*)Pw + wrbase + ch * 16) = pk;
        }

        const bf16x8 pa0 = *(const bf16x8*)(Pw + rd0);
        const bf16x8 pa1 = *(const bf16x8*)(Pw + rd1);

        // O += P V
#pragma unroll
        for (int ct = 0; ct < 4; ++ct) {
          const bf16x8 vb0 = *(const bf16x8*)&Vt[kof0[ct]];
          const bf16x8 vb1 = *(const bf16x8*)&Vt[kof1[ct]];
          oc[ct] = __builtin_amdgcn_mfma_f32_16x16x32_bf16(pa0, vb0, oc[ct], 0, 0, 0);
          oc[ct] = __builtin_amdgcn_mfma_f32_16x16x32_bf16(pa1, vb1, oc[ct], 0, 0, 0);
        }
      }
      __syncthreads();  // all reads of Ks/Vt done before next commit
    }
  }

  // epilogue (R8-proven): unnormalized partial O + per-row (m,l)
  const size_t pb = (size_t)(hz * BH_ + bh) * T_;
  if (lk == 0)
    ml_ws[pb + q0 + w * 16 + lrow] = make_float2(m_r, l_r);
#pragma unroll
  for (int i = 0; i < 4; ++i) {
    const int t = q0 + w * 16 + lk * 4 + i;
    ushort* orow = op_ws + (pb + t) * DH_;
#pragma unroll
    for (int ct = 0; ct < 4; ++ct)
      orow[ct * 16 + lrow] = f2bf(oc[ct][i]);
  }
}

// ---------------------------------------------------------------------------
// Out-proj GEMM with fused split-k combine (64x64 tiles, R9-proven).
// ---------------------------------------------------------------------------
__global__ __launch_bounds__(256) void proj_fused_k(
    const ushort* __restrict__ op_ws, const float2* __restrict__ ml_ws,
    const ushort* __restrict__ Wpt, const float* __restrict__ bp,
    float* __restrict__ out)
{
  __shared__ __align__(16) ushort lds[(64 + 64) * 64];  // As | Bs (16 KB)
  ushort* As = lds;
  ushort* Bs = lds + 64 * 64;

  const int n0 = blockIdx.x * 64;
  const int m0 = blockIdx.y * 64;
  const int b  = m0 >> 11;
  const int t0 = m0 & 2047;

  const int tid  = threadIdx.x;
  const int w    = tid >> 6, l = tid & 63;
  const int lrow = l & 15, lk = l >> 4;
  const int r7   = lrow & 7;
  const int srow = l >> 3;
  const int sch  = (l & 7) ^ srow;
  const int ar = tid >> 2;          // A-staging row 0..63
  const int cc = tid & 3;           // 16-elem chunk
  const int a7 = ar & 7;

  f32x4 acc[4] = {};

  for (int k0 = 0; k0 < E_; k0 += 64) {
    const int h  = k0 >> 6;
    const int bh = b * H_ + h;

#pragma unroll
    for (int r = 0; r < 2; ++r) {
      const int base = r * 32 + w * 8;
      gl16(Wpt + (size_t)(n0 + base + srow) * E_ + k0 + sch * 8, &Bs[base * 64]);
    }

    // A staging: combine NSPLIT partials in regs, swizzled ds_write
    {
      const int t = t0 + ar;
      size_t ix[NSPLIT];
      float2 ml[NSPLIT];
#pragma unroll
      for (int z = 0; z < NSPLIT; ++z) {
        ix[z] = ((size_t)(z * BH_ + bh) * T_ + t);
        ml[z] = ml_ws[ix[z]];
      }
      float m = ml[0].x;
#pragma unroll
      for (int z = 1; z < NSPLIT; ++z) m = fmaxf(m, ml[z].x);
      float f[NSPLIT];
      float den = 0.f;
#pragma unroll
      for (int z = 0; z < NSPLIT; ++z) {
        f[z] = exp2f(ml[z].x - m);
        den += f[z] * ml[z].y;
      }
      const float inv = 1.0f / den;
#pragma unroll
      for (int z = 0; z < NSPLIT; ++z) f[z] *= inv;

      float o[16] = {};
#pragma unroll
      for (int z = 0; z < NSPLIT; ++z) {
        const ushort* p = op_ws + ix[z] * DH_ + cc * 16;
        bf16x8 x0 = *(const bf16x8*)p;
        bf16x8 x1 = *(const bf16x8*)(p + 8);
#pragma unroll
        for (int j = 0; j < 8; ++j) {
          o[j]     += f[z] * bf2f((ushort)x0[j]);
          o[8 + j] += f[z] * bf2f((ushort)x1[j]);
        }
      }
      ushort ob[16];
#pragma unroll
      for (int j = 0; j < 16; ++j) ob[j] = f2bf(o[j]);
      *(bf16x8*)&As[ar * 64 + ((2 * cc) ^ a7) * 8]     = *(const bf16x8*)&ob[0];
      *(bf16x8*)&As[ar * 64 + ((2 * cc + 1) ^ a7) * 8] = *(const bf16x8*)&ob[8];
    }
    __syncthreads();

#pragma unroll
    for (int kk = 0; kk < 2; ++kk) {
      const int cof = ((kk * 4 + lk) ^ r7) * 8;
      const bf16x8 a = *(const bf16x8*)&As[(w * 16 + lrow) * 64 + cof];
#pragma unroll
      for (int nf = 0; nf < 4; ++nf) {
        const bf16x8 bb = *(const bf16x8*)&Bs[(nf * 16 + lrow) * 64 + cof];
        acc[nf] = __builtin_amdgcn_mfma_f32_16x16x32_bf16(a, bb, acc[nf], 0, 0, 0);
      }
    }
    __syncthreads();
  }

  float bias[4];
#pragma unroll
  for (int nf = 0; nf < 4; ++nf) bias[nf] = bp[n0 + nf * 16 + lrow];

#pragma unroll
  for (int i = 0; i < 4; ++i) {
    const int m = m0 + w * 16 + lk * 4 + i;
    float* orow = out + (size_t)m * E_ + n0;
#pragma unroll
    for (int nf = 0; nf < 4; ++nf)
      orow[nf * 16 + lrow] = acc[nf][i] + bias[nf];
  }
}

}  // namespace

extern "C" void kernel_launch(void* const* d_in, const int* in_sizes, int n_in,
                              void* d_out, int out_size, void* d_ws, size_t ws_size,
                              hipStream_t stream) {
  const float* x  = (const float*)d_in[0];
  const float* Wq = (const float*)d_in[1];
  const float* Wk = (const float*)d_in[2];
  const float* Wv = (const float*)d_in[3];
  const float* Wp = (const float*)d_in[4];
  const float* bp = (const float*)d_in[5];
  float* out = (float*)d_out;

  const size_t nx  = (size_t)M_ * E_;            // 3,145,728
  const size_t nwt = (size_t)3 * H_ * DH_ * E_;  // 1,769,472
  const size_t nwp = (size_t)E_ * E_;            // 589,824
  const size_t per = (size_t)BH_ * T_ * DH_;     // 3,145,728

  ushort* xb    = (ushort*)d_ws;
  ushort* Wt    = xb + nx;
  ushort* Wpt   = Wt + nwt;
  ushort* q_ws  = Wpt + nwp;
  ushort* k_ws  = q_ws + per;
  ushort* vt_ws = k_ws + per;     // [bh][d][t]
  ushort* op_ws = vt_ws + per;    // [NSPLIT][bh][t][64] partials
  float2* ml_ws = (float2*)(op_ws + NSPLIT * per);  // [NSPLIT][bh][t]

  prep_k<<<dim3(NCONV + 576), 256, 0, stream>>>(x, Wq, Wk, Wv, Wp, xb, Wt, Wpt);
  qkv_fused_k<<<dim3(36, 16), 512, 0, stream>>>(xb, Wt, q_ws, k_ws, vt_ws);
  attn_split_k<<<dim3(24, 16, NSPLIT), 512, 0, stream>>>(q_ws, k_ws, vt_ws, op_ws, ml_ws);
  proj_fused_k<<<dim3(12, 64), 256, 0, stream>>>(op_ws, ml_ws, Wpt, bp, out);
}

// Round 19
// 90.073 us; speedup vs baseline: 1.0601x; 1.0326x over previous
//
#include <hip/hip_runtime.h>
#include <math.h>

namespace {

constexpr int E_  = 768;
constexpr int H_  = 12;
constexpr int DH_ = 64;
constexpr int T_  = 2048;
constexpr int B_  = 2;
constexpr int M_  = B_ * T_;  // 4096
constexpr int BH_ = B_ * H_;  // 24
constexpr int NSPLIT = 2;     // attention k-range split factor

typedef __attribute__((ext_vector_type(8))) short bf16x8;
typedef __attribute__((ext_vector_type(4))) float f32x4;

__device__ inline ushort f2bf(float f) {
  union { float f; unsigned u; } v; v.f = f;
  unsigned u = v.u + 0x7FFFu + ((v.u >> 16) & 1u);  // RNE
  return (ushort)(u >> 16);
}
__device__ inline float bf2f(ushort u) {
  union { unsigned u; float f; } v; v.u = (unsigned)u << 16; return v.f;
}

// async global->LDS, 16B per lane (wave-uniform LDS base, per-lane global src)
__device__ __forceinline__ void gl16(const ushort* g, ushort* l) {
  __builtin_amdgcn_global_load_lds(
      (const __attribute__((address_space(1))) unsigned int*)(g),
      (__attribute__((address_space(3))) unsigned int*)(l), 16, 0, 0);
}

// ---------------------------------------------------------------------------
// prep: blocks [0,1536) convert x f32->bf16; blocks [1536,2112) transpose W.
// ---------------------------------------------------------------------------
constexpr int NCONV = 1536;

__global__ __launch_bounds__(256) void prep_k(
    const float* __restrict__ x,
    const float* __restrict__ Wq, const float* __restrict__ Wk,
    const float* __restrict__ Wv, const float* __restrict__ Wp,
    ushort* __restrict__ xb, ushort* __restrict__ Wt, ushort* __restrict__ Wpt)
{
  __shared__ float tile[64][65];
  const int bid = blockIdx.x;
  const int tid = threadIdx.x;

  if (bid < NCONV) {
    const size_t i = ((size_t)bid * 256 + tid) * 8;
    float4 a = *(const float4*)(x + i);
    float4 b = *(const float4*)(x + i + 4);
    ushort o[8] = {f2bf(a.x), f2bf(a.y), f2bf(a.z), f2bf(a.w),
                   f2bf(b.x), f2bf(b.y), f2bf(b.z), f2bf(b.w)};
    *(bf16x8*)(xb + i) = *(bf16x8*)o;
    return;
  }

  const int wb = bid - NCONV;  // 0..575
  const int tr = tid >> 4, tc = tid & 15;
  const float* src; ushort* dst;
  int k0, n0, sN, dK;
  if (wb < 432) {
    const int mat = wb / 144, rem = wb % 144;
    const int h = rem / 12, ktile = rem % 12;
    const float* W = (mat == 0) ? Wq : (mat == 1) ? Wk : Wv;
    src = W + (size_t)h * E_ * DH_;
    dst = Wt + (size_t)(mat * H_ + h) * DH_ * E_;
    k0 = ktile * 64; n0 = 0; sN = DH_; dK = E_;
  } else {
    const int rem = wb - 432;
    src = Wp;
    dst = Wpt;
    k0 = (rem / 12) * 64; n0 = (rem % 12) * 64; sN = E_; dK = E_;
  }

#pragma unroll
  for (int rr = 0; rr < 64; rr += 16) {
    float4 v = *(const float4*)(src + (size_t)(k0 + tr + rr) * sN + n0 + tc * 4);
    tile[tr + rr][tc * 4 + 0] = v.x;
    tile[tr + rr][tc * 4 + 1] = v.y;
    tile[tr + rr][tc * 4 + 2] = v.z;
    tile[tr + rr][tc * 4 + 3] = v.w;
  }
  __syncthreads();
#pragma unroll
  for (int rr = 0; rr < 64; rr += 16) {
    const int n = tr + rr;
    ushort4 o;
    o.x = f2bf(tile[tc * 4 + 0][n]);
    o.y = f2bf(tile[tc * 4 + 1][n]);
    o.z = f2bf(tile[tc * 4 + 2][n]);
    o.w = f2bf(tile[tc * 4 + 3][n]);
    *(ushort4*)(dst + (size_t)(n0 + n) * dK + k0 + tc * 4) = o;
  }
}

// ---------------------------------------------------------------------------
// QKV GEMM: 128x64 tiles, 256 threads (R16-exact, measured best).
// grid (36, 32) = 1152 blocks -> 4.5 blocks/CU.
// ---------------------------------------------------------------------------
constexpr float QSCALE = 0.18033688f;  // 1/8 * log2(e)

__global__ __launch_bounds__(256) void qkv_fused_k(
    const ushort* __restrict__ xb, const ushort* __restrict__ Wt,
    ushort* __restrict__ q_ws, ushort* __restrict__ k_ws, ushort* __restrict__ vt_ws)
{
  __shared__ __align__(16) ushort lds[(128 + 64) * 64];  // As | Bs (24 KB)
  ushort* As = lds;
  ushort* Bs = lds + 128 * 64;

  const int seg = blockIdx.x;        // 0..35: (mat, head)
  const int m0  = blockIdx.y * 128;
  const ushort* Wh = Wt + (size_t)seg * DH_ * E_;

  const int tid  = threadIdx.x;
  const int w    = tid >> 6, l = tid & 63;
  const int lrow = l & 15, lk = l >> 4;
  const int r7   = lrow & 7;
  const int srow = l >> 3;
  const int sch  = (l & 7) ^ srow;

  f32x4 acc[2][4] = {};

  for (int k0 = 0; k0 < E_; k0 += 64) {
#pragma unroll
    for (int r = 0; r < 4; ++r) {
      const int base = r * 32 + w * 8;
      gl16(xb + (size_t)(m0 + base + srow) * E_ + k0 + sch * 8, &As[base * 64]);
      if (r < 2)
        gl16(Wh + (size_t)(base + srow) * E_ + k0 + sch * 8, &Bs[base * 64]);
    }
    __syncthreads();

#pragma unroll
    for (int kk = 0; kk < 2; ++kk) {
      const int cof = ((kk * 4 + lk) ^ r7) * 8;
      const bf16x8 a0 = *(const bf16x8*)&As[(w * 32 + lrow) * 64 + cof];
      const bf16x8 a1 = *(const bf16x8*)&As[(w * 32 + 16 + lrow) * 64 + cof];
#pragma unroll
      for (int nf = 0; nf < 4; ++nf) {
        const bf16x8 b = *(const bf16x8*)&Bs[(nf * 16 + lrow) * 64 + cof];
        acc[0][nf] = __builtin_amdgcn_mfma_f32_16x16x32_bf16(a0, b, acc[0][nf], 0, 0, 0);
        acc[1][nf] = __builtin_amdgcn_mfma_f32_16x16x32_bf16(a1, b, acc[1][nf], 0, 0, 0);
      }
    }
    __syncthreads();
  }

  const int b   = m0 >> 11;
  const int t0  = m0 & 2047;
  const int mat = seg / H_;
  const int h   = seg - mat * H_;
  const int bh  = b * H_ + h;

  if (mat != 2) {
    const float qs = (mat == 0) ? QSCALE : 1.0f;
    ushort* outw = (mat == 0) ? q_ws : k_ws;
#pragma unroll
    for (int mi = 0; mi < 2; ++mi)
#pragma unroll
      for (int i = 0; i < 4; ++i) {
        const int t = t0 + w * 32 + mi * 16 + lk * 4 + i;
        ushort* orow = outw + ((size_t)bh * T_ + t) * DH_;
#pragma unroll
        for (int nf = 0; nf < 4; ++nf)
          orow[nf * 16 + lrow] = f2bf(acc[mi][nf][i] * qs);
      }
  } else {
    ushort* Td = lds;  // [64][136]
    __syncthreads();
#pragma unroll
    for (int mi = 0; mi < 2; ++mi)
#pragma unroll
      for (int i = 0; i < 4; ++i) {
        const int tl = w * 32 + mi * 16 + lk * 4 + i;
#pragma unroll
        for (int nf = 0; nf < 4; ++nf)
          Td[(nf * 16 + lrow) * 136 + tl] = f2bf(acc[mi][nf][i]);
      }
    __syncthreads();
#pragma unroll
    for (int it = 0; it < 4; ++it) {
      const int c = tid + it * 256;
      const int d = c >> 4, sub = c & 15;
      *(bf16x8*)(vt_ws + ((size_t)bh * DH_ + d) * T_ + t0 + sub * 8) =
          *(const bf16x8*)&Td[d * 136 + sub * 8];
    }
  }
}

// ---------------------------------------------------------------------------
// Causal flash attention — R16-EXACT (measured best): split x2, QBLK=128
// (512 threads), single-buffered K/V with 2 barriers/tile, 32 KB LDS,
// skip-guard for fully-masked waves, per-wave swizzled P bounce, defer-max,
// exp2 domain. grid (24, 16, 2), long q-tiles first.
// ---------------------------------------------------------------------------
__global__ __launch_bounds__(512) void attn_split_k(
    const ushort* __restrict__ q_ws, const ushort* __restrict__ k_ws,
    const ushort* __restrict__ vt_ws, ushort* __restrict__ op_ws,
    float2* __restrict__ ml_ws)
{
  __shared__ __align__(16) ushort Ks[64 * 64];     // K tile [s][e], swizzled
  __shared__ __align__(16) ushort Vt[64 * 64];     // V^T tile [d][s], swizzled
  __shared__ __align__(16) ushort Pl[8][16 * 64];  // per-wave P [q][s], swizzled

  const int qt = 15 - (int)blockIdx.y;     // 128-row q-tile, long first
  const int bh = blockIdx.x;
  const int hz = blockIdx.z;               // 0..NSPLIT-1
  const int nt = 2 * qt + 2;               // 64-wide k-tiles in causal range
  const int klo = (hz * nt) / NSPLIT;
  const int khi = ((hz + 1) * nt) / NSPLIT;
  const int q0 = qt * 128;

  const ushort* Qb  = q_ws + (size_t)bh * T_ * DH_;
  const ushort* Kb  = k_ws + (size_t)bh * T_ * DH_;
  const ushort* VTb = vt_ws + (size_t)bh * DH_ * T_;

  const int tid  = threadIdx.x;
  const int w    = tid >> 6;        // 0..7
  const int l    = tid & 63;
  const int lrow = l & 15;
  const int lk   = l >> 4;
  const int r7   = lrow & 7;
  const int rr   = tid >> 3;        // staging row 0..63
  const int sub  = tid & 7;
  const int swc  = sub ^ (rr & 7);

  const int st0 = rr * 64 + swc * 8;

  int kof0[4], kof1[4];
#pragma unroll
  for (int ct = 0; ct < 4; ++ct) {
    kof0[ct] = (ct * 16 + lrow) * 64 + ((lk ^ r7) * 8);
    kof1[ct] = (ct * 16 + lrow) * 64 + (((lk + 4) ^ r7) * 8);
  }

  const ushort* Qrow = Qb + (size_t)(q0 + w * 16 + lrow) * DH_;
  const bf16x8 qa0 = *(const bf16x8*)(Qrow + lk * 8);
  const bf16x8 qa1 = *(const bf16x8*)(Qrow + lk * 8 + 32);
  const int qglob = q0 + w * 16 + lrow;
  const int qwmin = q0 + w * 16;

  float m_r = -INFINITY, l_r = 0.f;
  f32x4 oc[4] = {};

  ushort* Pw = &Pl[w][0];
  const int rd0 = lrow * 64 + ((lk ^ r7) * 8);
  const int rd1 = lrow * 64 + (((lk + 4) ^ r7) * 8);
  const int wrbase  = lrow * 128 + (lk & 1) * 8;
  const int wrchunk = (lk >> 1);

  {
    // prologue: tile klo -> regs
    bf16x8 kp = *(const bf16x8*)(Kb + (size_t)(klo * 64 + rr) * DH_ + sub * 8);
    bf16x8 vp = *(const bf16x8*)(VTb + (size_t)rr * T_ + klo * 64 + sub * 8);

    for (int kt = klo; kt < khi; ++kt) {
      const int s0 = kt * 64;

      // commit staged regs -> LDS; barrier opens compute phase
      *(bf16x8*)&Ks[st0] = kp;
      *(bf16x8*)&Vt[st0] = vp;
      __syncthreads();

      // issue next tile's global loads; latency hides under compute
      if (kt + 1 < khi) {
        const int sn = s0 + 64;
        kp = *(const bf16x8*)(Kb + (size_t)(sn + rr) * DH_ + sub * 8);
        vp = *(const bf16x8*)(VTb + (size_t)rr * T_ + sn + sub * 8);
      }

      // wave-uniform: s0 > qwmin => tile fully masked for this wave -> skip
      if (s0 <= qwmin) {
        // S^T = K Q^T
        f32x4 st[4];
#pragma unroll
        for (int ct = 0; ct < 4; ++ct) {
          const bf16x8 kb0 = *(const bf16x8*)&Ks[kof0[ct]];
          const bf16x8 kb1 = *(const bf16x8*)&Ks[kof1[ct]];
          f32x4 z = {0.f, 0.f, 0.f, 0.f};
          z = __builtin_amdgcn_mfma_f32_16x16x32_bf16(kb0, qa0, z, 0, 0, 0);
          st[ct] = __builtin_amdgcn_mfma_f32_16x16x32_bf16(kb1, qa1, z, 0, 0, 0);
        }

        if (s0 + 63 > qwmin) {  // partial (diagonal) tile for this wave
#pragma unroll
          for (int ct = 0; ct < 4; ++ct)
#pragma unroll
            for (int i = 0; i < 4; ++i)
              if (s0 + ct * 16 + lk * 4 + i > qglob) st[ct][i] = -INFINITY;
        }

        float mc[4];
#pragma unroll
        for (int ct = 0; ct < 4; ++ct)
          mc[ct] = fmaxf(fmaxf(st[ct][0], st[ct][1]), fmaxf(st[ct][2], st[ct][3]));
        float mx = fmaxf(fmaxf(mc[0], mc[1]), fmaxf(mc[2], mc[3]));
        mx = fmaxf(mx, __shfl_xor(mx, 16));
        mx = fmaxf(mx, __shfl_xor(mx, 32));

        if (__any(mx > m_r + 8.f)) {
          const float mn   = fmaxf(m_r, mx);
          const float corr = exp2f(m_r - mn);
          m_r = mn;
          l_r *= corr;
#pragma unroll
          for (int i = 0; i < 4; ++i) {
            const float cr = __shfl(corr, lk * 4 + i);
#pragma unroll
            for (int ct = 0; ct < 4; ++ct) oc[ct][i] *= cr;
          }
        }

        float sc[4];
#pragma unroll
        for (int ct = 0; ct < 4; ++ct) {
#pragma unroll
          for (int i = 0; i < 4; ++i) st[ct][i] = exp2f(st[ct][i] - m_r);
          sc[ct] = (st[ct][0] + st[ct][1]) + (st[ct][2] + st[ct][3]);
        }
        float rs = (sc[0] + sc[1]) + (sc[2] + sc[3]);
        rs += __shfl_xor(rs, 16);
        rs += __shfl_xor(rs, 32);
        l_r += rs;

        // P^T -> per-wave LDS (packed bf16, swizzled 8B stores; no barrier)
#pragma unroll
        for (int ct = 0; ct < 4; ++ct) {
          unsigned lo, hi;
          asm("v_cvt_pk_bf16_f32 %0, %1, %2" : "=v"(lo) : "v"(st[ct][0]), "v"(st[ct][1]));
          asm("v_cvt_pk_bf16_f32 %0, %1, %2" : "=v"(hi) : "v"(st[ct][2]), "v"(st[ct][3]));
          uint2 pk; pk.x = lo; pk.y = hi;
          const int ch = ((ct * 2 + wrchunk) ^ r7);
          *(uint2*)((char*)Pw + wrbase + ch * 16) = pk;
        }

        const bf16x8 pa0 = *(const bf16x8*)(Pw + rd0);
        const bf16x8 pa1 = *(const bf16x8*)(Pw + rd1);

        // O += P V
#pragma unroll
        for (int ct = 0; ct < 4; ++ct) {
          const bf16x8 vb0 = *(const bf16x8*)&Vt[kof0[ct]];
          const bf16x8 vb1 = *(const bf16x8*)&Vt[kof1[ct]];
          oc[ct] = __builtin_amdgcn_mfma_f32_16x16x32_bf16(pa0, vb0, oc[ct], 0, 0, 0);
          oc[ct] = __builtin_amdgcn_mfma_f32_16x16x32_bf16(pa1, vb1, oc[ct], 0, 0, 0);
        }
      }
      __syncthreads();  // all reads of Ks/Vt done before next commit
    }
  }

  // epilogue (R8-proven): unnormalized partial O + per-row (m,l)
  const size_t pb = (size_t)(hz * BH_ + bh) * T_;
  if (lk == 0)
    ml_ws[pb + q0 + w * 16 + lrow] = make_float2(m_r, l_r);
#pragma unroll
  for (int i = 0; i < 4; ++i) {
    const int t = q0 + w * 16 + lk * 4 + i;
    ushort* orow = op_ws + (pb + t) * DH_;
#pragma unroll
    for (int ct = 0; ct < 4; ++ct)
      orow[ct * 16 + lrow] = f2bf(oc[ct][i]);
  }
}

// ---------------------------------------------------------------------------
// Out-proj GEMM with fused split-k combine (64x64 tiles, R9-proven).
// Handles (m=-inf, l=0) padding splits exactly: exp2(-inf - m) = 0.
// ---------------------------------------------------------------------------
__global__ __launch_bounds__(256) void proj_fused_k(
    const ushort* __restrict__ op_ws, const float2* __restrict__ ml_ws,
    const ushort* __restrict__ Wpt, const float* __restrict__ bp,
    float* __restrict__ out)
{
  __shared__ __align__(16) ushort lds[(64 + 64) * 64];  // As | Bs (16 KB)
  ushort* As = lds;
  ushort* Bs = lds + 64 * 64;

  const int n0 = blockIdx.x * 64;
  const int m0 = blockIdx.y * 64;
  const int b  = m0 >> 11;
  const int t0 = m0 & 2047;

  const int tid  = threadIdx.x;
  const int w    = tid >> 6, l = tid & 63;
  const int lrow = l & 15, lk = l >> 4;
  const int r7   = lrow & 7;
  const int srow = l >> 3;
  const int sch  = (l & 7) ^ srow;
  const int ar = tid >> 2;          // A-staging row 0..63
  const int cc = tid & 3;           // 16-elem chunk
  const int a7 = ar & 7;

  f32x4 acc[4] = {};

  for (int k0 = 0; k0 < E_; k0 += 64) {
    const int h  = k0 >> 6;
    const int bh = b * H_ + h;

#pragma unroll
    for (int r = 0; r < 2; ++r) {
      const int base = r * 32 + w * 8;
      gl16(Wpt + (size_t)(n0 + base + srow) * E_ + k0 + sch * 8, &Bs[base * 64]);
    }

    // A staging: combine NSPLIT partials in regs, swizzled ds_write
    {
      const int t = t0 + ar;
      size_t ix[NSPLIT];
      float2 ml[NSPLIT];
#pragma unroll
      for (int z = 0; z < NSPLIT; ++z) {
        ix[z] = ((size_t)(z * BH_ + bh) * T_ + t);
        ml[z] = ml_ws[ix[z]];
      }
      float m = ml[0].x;
#pragma unroll
      for (int z = 1; z < NSPLIT; ++z) m = fmaxf(m, ml[z].x);
      float f[NSPLIT];
      float den = 0.f;
#pragma unroll
      for (int z = 0; z < NSPLIT; ++z) {
        f[z] = exp2f(ml[z].x - m);
        den += f[z] * ml[z].y;
      }
      const float inv = 1.0f / den;
#pragma unroll
      for (int z = 0; z < NSPLIT; ++z) f[z] *= inv;

      float o[16] = {};
#pragma unroll
      for (int z = 0; z < NSPLIT; ++z) {
        const ushort* p = op_ws + ix[z] * DH_ + cc * 16;
        bf16x8 x0 = *(const bf16x8*)p;
        bf16x8 x1 = *(const bf16x8*)(p + 8);
#pragma unroll
        for (int j = 0; j < 8; ++j) {
          o[j]     += f[z] * bf2f((ushort)x0[j]);
          o[8 + j] += f[z] * bf2f((ushort)x1[j]);
        }
      }
      ushort ob[16];
#pragma unroll
      for (int j = 0; j < 16; ++j) ob[j] = f2bf(o[j]);
      *(bf16x8*)&As[ar * 64 + ((2 * cc) ^ a7) * 8]     = *(const bf16x8*)&ob[0];
      *(bf16x8*)&As[ar * 64 + ((2 * cc + 1) ^ a7) * 8] = *(const bf16x8*)&ob[8];
    }
    __syncthreads();

#pragma unroll
    for (int kk = 0; kk < 2; ++kk) {
      const int cof = ((kk * 4 + lk) ^ r7) * 8;
      const bf16x8 a = *(const bf16x8*)&As[(w * 16 + lrow) * 64 + cof];
#pragma unroll
      for (int nf = 0; nf < 4; ++nf) {
        const bf16x8 bb = *(const bf16x8*)&Bs[(nf * 16 + lrow) * 64 + cof];
        acc[nf] = __builtin_amdgcn_mfma_f32_16x16x32_bf16(a, bb, acc[nf], 0, 0, 0);
      }
    }
    __syncthreads();
  }

  float bias[4];
#pragma unroll
  for (int nf = 0; nf < 4; ++nf) bias[nf] = bp[n0 + nf * 16 + lrow];

#pragma unroll
  for (int i = 0; i < 4; ++i) {
    const int m = m0 + w * 16 + lk * 4 + i;
    float* orow = out + (size_t)m * E_ + n0;
#pragma unroll
    for (int nf = 0; nf < 4; ++nf)
      orow[nf * 16 + lrow] = acc[nf][i] + bias[nf];
  }
}

}  // namespace

extern "C" void kernel_launch(void* const* d_in, const int* in_sizes, int n_in,
                              void* d_out, int out_size, void* d_ws, size_t ws_size,
                              hipStream_t stream) {
  const float* x  = (const float*)d_in[0];
  const float* Wq = (const float*)d_in[1];
  const float* Wk = (const float*)d_in[2];
  const float* Wv = (const float*)d_in[3];
  const float* Wp = (const float*)d_in[4];
  const float* bp = (const float*)d_in[5];
  float* out = (float*)d_out;

  const size_t nx  = (size_t)M_ * E_;            // 3,145,728
  const size_t nwt = (size_t)3 * H_ * DH_ * E_;  // 1,769,472
  const size_t nwp = (size_t)E_ * E_;            // 589,824
  const size_t per = (size_t)BH_ * T_ * DH_;     // 3,145,728

  ushort* xb    = (ushort*)d_ws;
  ushort* Wt    = xb + nx;
  ushort* Wpt   = Wt + nwt;
  ushort* q_ws  = Wpt + nwp;
  ushort* k_ws  = q_ws + per;
  ushort* vt_ws = k_ws + per;     // [bh][d][t]
  ushort* op_ws = vt_ws + per;    // [NSPLIT][bh][t][64] partials
  float2* ml_ws = (float2*)(op_ws + NSPLIT * per);  // [NSPLIT][bh][t]

  prep_k<<<dim3(NCONV + 576), 256, 0, stream>>>(x, Wq, Wk, Wv, Wp, xb, Wt, Wpt);
  qkv_fused_k<<<dim3(36, 32), 256, 0, stream>>>(xb, Wt, q_ws, k_ws, vt_ws);
  attn_split_k<<<dim3(24, 16, NSPLIT), 512, 0, stream>>>(q_ws, k_ws, vt_ws, op_ws, ml_ws);
  proj_fused_k<<<dim3(12, 64), 256, 0, stream>>>(op_ws, ml_ws, Wpt, bp, out);
}